// Round 2
// baseline (511.335 us; speedup 1.0000x reference)
//
#include <hip/hip_runtime.h>

#define D_DIM 764
#define DP    768
#define BM    128
#define BN    128
#define BK    64

typedef __attribute__((ext_vector_type(8))) short bf16x8;
typedef __attribute__((ext_vector_type(4))) float f32x4;

typedef __attribute__((address_space(3))) char lds_char;
typedef __attribute__((address_space(1))) const char g_char;

__device__ inline unsigned short f2bf(float f) {
    union { float f; unsigned u; } v; v.f = f;
    unsigned r = v.u + 0x7FFFu + ((v.u >> 16) & 1u);  // RNE
    return (unsigned short)(r >> 16);
}

// Mask (k < n), cast to bf16, pad to DP x DP. Layout: Wb[n][k] (BT form, K-contiguous).
__global__ void prep_w(const float* __restrict__ W, unsigned short* __restrict__ Wb) {
    int idx = blockIdx.x * blockDim.x + threadIdx.x;   // 0 .. DP*DP-1
    int n = idx / DP, k = idx - n * DP;
    float v = 0.0f;
    if (n < D_DIM && k < n) v = W[n * D_DIM + k];
    Wb[idx] = f2bf(v);
}

// v3: A never touches LDS. Each wave (32x64 tile, 8 waves) loads its own A
// fragments global->regs (2x dwordx4/lane/frag), converts in-register.
// B triple-buffered in LDS via global_load_lds; ONE raw s_barrier per K-step
// with counted vmcnt(10) (= this iteration's 8 A-loads + 2 B-DMAs) so next
// tile's loads stay in flight across the barrier. 3 buffers => a buffer is
// overwritten 3 tiles after its last read with >=1 barrier in between (safe).
__global__ __launch_bounds__(512, 4) void fvsbn_gemm(
    const float* __restrict__ X,          // [65536, 764] fp32
    const unsigned short* __restrict__ Wb,// [768, 768] bf16 masked (BT layout)
    const float* __restrict__ bias,       // [764] fp32
    float* __restrict__ out)              // [65536, 764] fp32
{
    __shared__ __align__(16) unsigned short Bs[3][BN * BK]; // 3 x 16 KB

    const int tid  = threadIdx.x;
    const int lane = tid & 63;
    const int wid  = tid >> 6;        // 0..7
    const int wm   = wid & 3;         // 32-row m-slice
    const int wn   = wid >> 2;        // 64-col n-slice
    const int quad = lane >> 4;
    const int l16  = lane & 15;

    // XCD-aware swizzle: 512 m-tiles x 6 n-tiles, contiguous m per XCD.
    const int bid = blockIdx.x;       // 0..3071
    const int xcd = bid & 7;
    const int j   = bid >> 3;         // 0..383
    const int nt  = j % 6;
    const int jm  = j / 6;            // 0..63
    const int mt  = jm * 8 + xcd;     // 0..511
    const int m0  = mt * BM;
    const int n0  = nt * BN;

    // Triangular skip: cols [n0, n0+127] need k <= n0+126.
    const int num_k = (n0 + BN) / BK;  // 2,4,6,8,10,12

    // ---- B staging descriptors (linear LDS dest, source-swizzled) ----
    const unsigned short* bsrc[2];
    int bofs[2];
#pragma unroll
    for (int jj = 0; jj < 2; ++jj) {
        const int cbase = (wid * 2 + jj) * 64;       // wave-uniform chunk base
        const int c     = cbase + lane;              // 0..1023
        const int r     = c >> 3;
        const int cc    = c & 7;
        const int g     = cc ^ (r & 7);              // swizzled global chunk
        bsrc[jj] = Wb + (size_t)(n0 + r) * DP + g * 8;
        bofs[jj] = cbase * 16;
    }

    // ---- A fragment pointers: f = s*2 + mi ; per-lane 8 consecutive k ----
    const float* aptr[4];
    int hisel[4];
#pragma unroll
    for (int s = 0; s < 2; ++s)
#pragma unroll
        for (int mi = 0; mi < 2; ++mi) {
            const int f   = s * 2 + mi;
            const int row = m0 + wm * 32 + mi * 16 + l16;
            const int kb  = s * 32 + quad * 8;
            aptr[f]  = X + (size_t)row * D_DIM + kb;
            // hi half (k+4..k+7) valid iff k0 <= hisel; else re-read lo addr:
            // those k are 764..767 where Wb is zero, so garbage*0 = 0.
            hisel[f] = D_DIM - 8 - kb;
        }

    f32x4 acc[2][4];
#pragma unroll
    for (int mi = 0; mi < 2; ++mi)
#pragma unroll
        for (int ni = 0; ni < 4; ++ni) acc[mi][ni] = (f32x4){0.f, 0.f, 0.f, 0.f};

    float4 alo[4], ahi[4];
    bf16x8 afr[4];

#define STAGE_B(buf, k0s)                                                   \
    _Pragma("unroll")                                                       \
    for (int jj = 0; jj < 2; ++jj)                                          \
        __builtin_amdgcn_global_load_lds((g_char*)(bsrc[jj] + (k0s)),       \
            (lds_char*)((char*)&Bs[buf][0] + bofs[jj]), 16, 0, 0);

#define LOAD_A(k0s)                                                         \
    _Pragma("unroll")                                                       \
    for (int f = 0; f < 4; ++f) {                                           \
        const float* lp = aptr[f] + (k0s);                                  \
        alo[f] = *(const float4*)lp;                                        \
        const float* hp = lp + (((k0s) <= hisel[f]) ? 4 : 0);               \
        ahi[f] = *(const float4*)hp;   /* always issues exactly 1 load */   \
    }

#define CONVERT()                                                           \
    _Pragma("unroll")                                                       \
    for (int f = 0; f < 4; ++f) {                                           \
        bf16x8 a;                                                           \
        a[0] = (short)f2bf(alo[f].x); a[1] = (short)f2bf(alo[f].y);         \
        a[2] = (short)f2bf(alo[f].z); a[3] = (short)f2bf(alo[f].w);         \
        a[4] = (short)f2bf(ahi[f].x); a[5] = (short)f2bf(ahi[f].y);         \
        a[6] = (short)f2bf(ahi[f].z); a[7] = (short)f2bf(ahi[f].w);         \
        afr[f] = a;                                                         \
    }

#define COMPUTE(buf)                                                        \
    _Pragma("unroll")                                                       \
    for (int s = 0; s < 2; ++s) {                                           \
        bf16x8 bfr[4];                                                      \
        _Pragma("unroll")                                                   \
        for (int ni = 0; ni < 4; ++ni) {                                    \
            const int r = wn * 64 + ni * 16 + l16;                          \
            const int g = s * 4 + quad;                                     \
            bfr[ni] = *(const bf16x8*)&Bs[buf][r * BK + (g ^ (r & 7)) * 8]; \
        }                                                                   \
        _Pragma("unroll")                                                   \
        for (int mi = 0; mi < 2; ++mi)                                      \
            _Pragma("unroll")                                               \
            for (int ni = 0; ni < 4; ++ni)                                  \
                acc[mi][ni] = __builtin_amdgcn_mfma_f32_16x16x32_bf16(      \
                    afr[s * 2 + mi], bfr[ni], acc[mi][ni], 0, 0, 0);        \
    }

    // ---- prologue: issue tile 0 (2 B-DMAs + 8 A-loads) ----
    STAGE_B(0, 0);
    LOAD_A(0);

    int cur = 0;
    for (int kk = 0; kk < num_k; ++kk) {
        CONVERT();                         // waits tile-kk A regs (compiler vmcnt)
        const int nxt = (cur == 2) ? 0 : cur + 1;
        if (kk + 1 < num_k) {
            const int k0n = (kk + 1) * BK;
            STAGE_B(nxt, k0n);             // 2 B-DMAs for tile kk+1
            LOAD_A(k0n);                   // 8 A-loads for tile kk+1
            // all but this iteration's 10 loads have landed (incl. my tile-kk B)
            asm volatile("s_waitcnt vmcnt(10)" ::: "memory");
        } else {
            asm volatile("s_waitcnt vmcnt(0)" ::: "memory");
        }
        __builtin_amdgcn_s_barrier();      // all waves' tile-kk B-DMAs landed
        __builtin_amdgcn_sched_barrier(0); // keep ds_reads below the barrier
        COMPUTE(cur);
        cur = nxt;
    }

    // ---- epilogue: + bias, store fp32 (col bound-checked vs 764) ----
#pragma unroll
    for (int ni = 0; ni < 4; ++ni) {
        const int col = n0 + wn * 64 + ni * 16 + l16;
        if (col < D_DIM) {
            const float bv = bias[col];
#pragma unroll
            for (int mi = 0; mi < 2; ++mi) {
                const int row = m0 + wm * 32 + mi * 16 + quad * 4;
#pragma unroll
                for (int r = 0; r < 4; ++r)
                    out[(size_t)(row + r) * D_DIM + col] = acc[mi][ni][r] + bv;
            }
        }
    }
#undef STAGE_B
#undef LOAD_A
#undef CONVERT
#undef COMPUTE
}

extern "C" void kernel_launch(void* const* d_in, const int* in_sizes, int n_in,
                              void* d_out, int out_size, void* d_ws, size_t ws_size,
                              hipStream_t stream) {
    const float* X    = (const float*)d_in[0];
    const float* W    = (const float*)d_in[1];
    const float* bias = (const float*)d_in[2];
    float* out        = (float*)d_out;
    unsigned short* Wb = (unsigned short*)d_ws;  // DP*DP bf16 = 1.18 MB

    prep_w<<<(DP * DP) / 256, 256, 0, stream>>>(W, Wb);
    fvsbn_gemm<<<(65536 / BM) * (DP / BN), 512, 0, stream>>>(X, Wb, bias, out);
}

// Round 3
// 414.493 us; speedup vs baseline: 1.2336x; 1.2336x over previous
//
#include <hip/hip_runtime.h>

#define D_DIM 764
#define DP    768
#define BM    128
#define BN    128
#define BK    64

typedef __attribute__((ext_vector_type(8))) short bf16x8;
typedef __attribute__((ext_vector_type(8))) unsigned short u16x8;
typedef __attribute__((ext_vector_type(4))) float f32x4;

typedef __attribute__((address_space(3))) char lds_char;
typedef __attribute__((address_space(1))) const char g_char;

__device__ inline unsigned short f2bf(float f) {
    union { float f; unsigned u; } v; v.f = f;
    unsigned r = v.u + 0x7FFFu + ((v.u >> 16) & 1u);  // RNE
    return (unsigned short)(r >> 16);
}

// Mask (k < n), cast to bf16, pad to DP x DP. Layout: Wb[n][k] (BT form, K-contiguous).
__global__ void prep_w(const float* __restrict__ W, unsigned short* __restrict__ Wb) {
    int idx = blockIdx.x * blockDim.x + threadIdx.x;   // 0 .. DP*DP-1
    int n = idx / DP, k = idx - n * DP;
    float v = 0.0f;
    if (n < D_DIM && k < n) v = W[n * D_DIM + k];
    Wb[idx] = f2bf(v);
}

// v4: v2's data paths (A global->reg->bf16->LDS dedup'd; B global_load_lds)
// with a real software pipeline: prefetch distance ~2 K-tiles, counted
// s_waitcnt vmcnt(6) (never 0 mid-loop), ONE raw s_barrier per K-step.
// Per iter t: issue{B(t+2) DMA, A(t+2)->regs}; COMPUTE(t); vmcnt(6)
// [= all of iter t-1's loads: A(t+1) regs + B(t+1) DMA landed];
// WRITE_A(t+1); lgkmcnt(0); s_barrier.
// A dbuf (rewrite 1 barrier after last read), B tribuf (DMA target's last
// reader is 2 barriers upstream). num_k always even -> unroll-2 loop with
// statically named A reg sets (no scratch).
__global__ __launch_bounds__(512, 4) void fvsbn_gemm(
    const float* __restrict__ X,          // [65536, 764] fp32
    const unsigned short* __restrict__ Wb,// [768, 768] bf16 masked (BT layout)
    const float* __restrict__ bias,       // [764] fp32
    float* __restrict__ out)              // [65536, 764] fp32
{
    __shared__ __align__(16) unsigned short As[2][BM * BK]; // 32 KB
    __shared__ __align__(16) unsigned short Bs[3][BN * BK]; // 48 KB

    const int tid  = threadIdx.x;
    const int lane = tid & 63;
    const int wid  = tid >> 6;        // 0..7
    const int wm   = wid & 3;         // 32-row m-slice
    const int wn   = wid >> 2;        // 64-col n-slice
    const int quad = lane >> 4;
    const int l16  = lane & 15;

    // XCD-aware swizzle: 512 m-tiles x 6 n-tiles, contiguous m per XCD.
    const int bid = blockIdx.x;       // 0..3071
    const int xcd = bid & 7;
    const int j   = bid >> 3;         // 0..383
    const int nt  = j % 6;
    const int jm  = j / 6;            // 0..63
    const int mt  = jm * 8 + xcd;     // 0..511
    const int m0  = mt * BM;
    const int n0  = nt * BN;

    // Triangular skip: cols [n0, n0+127] need k <= n0+126.
    const int num_k = (n0 + BN) / BK;  // 2,4,6,8,10,12 (always even)

    // ---- B staging descriptors (linear LDS dest, source-swizzled) ----
    const unsigned short* bsrc[2];
    int bofs[2];
#pragma unroll
    for (int jj = 0; jj < 2; ++jj) {
        const int cbase = (wid * 2 + jj) * 64;       // wave-uniform chunk base
        const int c     = cbase + lane;              // 0..1023
        const int r     = c >> 3;
        const int cc    = c & 7;
        const int g     = cc ^ (r & 7);              // swizzled global chunk
        bsrc[jj] = Wb + (size_t)(n0 + r) * DP + g * 8;
        bofs[jj] = cbase * 16;
    }

    // ---- A staging descriptors: 2 positions/thread (1024 = 128 rows x 8) ----
    const float* asrc[2];
    int adst[2], hilim[2];
#pragma unroll
    for (int i = 0; i < 2; ++i) {
        const int p  = tid + i * 512;                // 0..1023
        const int r  = p >> 3;
        const int cc = p & 7;
        const int g  = cc ^ (r & 7);
        asrc[i]  = X + (size_t)(m0 + r) * D_DIM + g * 8;
        adst[i]  = r * BK + cc * 8;
        hilim[i] = D_DIM - 8 - g * 8;  // hi float4 valid iff k0 <= hilim[i]
    }

    f32x4 acc[2][4];
#pragma unroll
    for (int mi = 0; mi < 2; ++mi)
#pragma unroll
        for (int ni = 0; ni < 4; ++ni) acc[mi][ni] = (f32x4){0.f, 0.f, 0.f, 0.f};

    // Two statically-named A register sets (even tiles -> set0, odd -> set1).
    float4 aLo0[2], aHi0[2], aLo1[2], aHi1[2];

#define STAGE_B(buf, k0s)                                                   \
    _Pragma("unroll")                                                       \
    for (int jj = 0; jj < 2; ++jj)                                          \
        __builtin_amdgcn_global_load_lds((g_char*)(bsrc[jj] + (k0s)),       \
            (lds_char*)((char*)&Bs[0][0] + (buf) * (BN * BK * 2) + bofs[jj]),\
            16, 0, 0);

#define LOAD_A(LO, HI, k0s)                                                 \
    _Pragma("unroll")                                                       \
    for (int i = 0; i < 2; ++i) {                                           \
        const float* lp = asrc[i] + (k0s);                                  \
        LO[i] = *(const float4*)lp;                                         \
        const float* hp = lp + (((k0s) <= hilim[i]) ? 4 : 0);               \
        HI[i] = *(const float4*)hp; /* OOB-safe: k>=764 pairs with Wb==0 */ \
    }

#define WRITE_A(LO, HI, abuf)                                               \
    _Pragma("unroll")                                                       \
    for (int i = 0; i < 2; ++i) {                                           \
        u16x8 pk;                                                           \
        pk[0] = f2bf(LO[i].x); pk[1] = f2bf(LO[i].y);                       \
        pk[2] = f2bf(LO[i].z); pk[3] = f2bf(LO[i].w);                       \
        pk[4] = f2bf(HI[i].x); pk[5] = f2bf(HI[i].y);                       \
        pk[6] = f2bf(HI[i].z); pk[7] = f2bf(HI[i].w);                       \
        *(u16x8*)&As[abuf][adst[i]] = pk;                                   \
    }

#define COMPUTE(abuf, bbase)                                                \
    _Pragma("unroll")                                                       \
    for (int s = 0; s < 2; ++s) {                                           \
        bf16x8 af[2], bfr[4];                                               \
        _Pragma("unroll")                                                   \
        for (int mi = 0; mi < 2; ++mi) {                                    \
            const int r = wm * 32 + mi * 16 + l16;                          \
            const int g = s * 4 + quad;                                     \
            af[mi] = *(const bf16x8*)&As[abuf][r * BK + (g ^ (r & 7)) * 8]; \
        }                                                                   \
        _Pragma("unroll")                                                   \
        for (int ni = 0; ni < 4; ++ni) {                                    \
            const int r = wn * 64 + ni * 16 + l16;                          \
            const int g = s * 4 + quad;                                     \
            bfr[ni] = *(const bf16x8*)&(bbase)[r * BK + (g ^ (r & 7)) * 8]; \
        }                                                                   \
        __builtin_amdgcn_s_setprio(1);                                      \
        _Pragma("unroll")                                                   \
        for (int mi = 0; mi < 2; ++mi)                                      \
            _Pragma("unroll")                                               \
            for (int ni = 0; ni < 4; ++ni)                                  \
                acc[mi][ni] = __builtin_amdgcn_mfma_f32_16x16x32_bf16(      \
                    af[mi], bfr[ni], acc[mi][ni], 0, 0, 0);                 \
        __builtin_amdgcn_s_setprio(0);                                      \
    }

    // ---- prologue: tiles 0 and 1 in flight, A(0) committed to LDS ----
    STAGE_B(0, 0);                 // B(0) DMA
    LOAD_A(aLo0, aHi0, 0);         // A(0) regs
    STAGE_B(1, BK);                // B(1) DMA
    LOAD_A(aLo1, aHi1, BK);        // A(1) regs
    asm volatile("s_waitcnt vmcnt(6)" ::: "memory");  // A(0)+B(0) landed
    WRITE_A(aLo0, aHi0, 0);
    asm volatile("s_waitcnt lgkmcnt(0)" ::: "memory");
    __builtin_amdgcn_s_barrier();
    __builtin_amdgcn_sched_barrier(0);

    int bcur = 0;  // B(t) lives in Bs[bcur] at loop top (t even)
    for (int t = 0; t < num_k; t += 2) {
        const bool more = (t + 2 < num_k);
        const int  b1   = (bcur == 2) ? 0 : bcur + 1;   // (bcur+1)%3
        const int  b2   = (bcur == 0) ? 2 : bcur - 1;   // (bcur+2)%3

        // ---- iter t (even): set0 free, set1 holds A(t+1) ----
        if (more) {
            STAGE_B(b2, (t + 2) * BK);          // B(t+2) DMA
            LOAD_A(aLo0, aHi0, (t + 2) * BK);   // A(t+2) -> set0
        }
        COMPUTE(0, &As[0][0] == nullptr ? (const unsigned short*)0 : &Bs[bcur][0]);
        if (more) { asm volatile("s_waitcnt vmcnt(6)" ::: "memory"); }
        else      { asm volatile("s_waitcnt vmcnt(0)" ::: "memory"); }
        WRITE_A(aLo1, aHi1, 1);                 // A(t+1) -> As[1]
        asm volatile("s_waitcnt lgkmcnt(0)" ::: "memory");
        __builtin_amdgcn_s_barrier();
        __builtin_amdgcn_sched_barrier(0);

        // ---- iter t+1 (odd): set1 free, set0 holds A(t+2) ----
        if (more) {
            STAGE_B(bcur, (t + 3) * BK);        // B(t+3) -> Bs[(bcur+3)%3]
            LOAD_A(aLo1, aHi1, (t + 3) * BK);   // A(t+3) -> set1
        }
        COMPUTE(1, &Bs[b1][0]);
        if (more) {
            asm volatile("s_waitcnt vmcnt(6)" ::: "memory");
            WRITE_A(aLo0, aHi0, 0);             // A(t+2) -> As[0]
            asm volatile("s_waitcnt lgkmcnt(0)" ::: "memory");
        }
        __builtin_amdgcn_s_barrier();
        __builtin_amdgcn_sched_barrier(0);
        bcur = b2;
    }

    // ---- epilogue: + bias, store fp32 (col bound-checked vs 764) ----
#pragma unroll
    for (int ni = 0; ni < 4; ++ni) {
        const int col = n0 + wn * 64 + ni * 16 + l16;
        if (col < D_DIM) {
            const float bv = bias[col];
#pragma unroll
            for (int mi = 0; mi < 2; ++mi) {
                const int row = m0 + wm * 32 + mi * 16 + quad * 4;
#pragma unroll
                for (int r = 0; r < 4; ++r)
                    out[(size_t)(row + r) * D_DIM + col] = acc[mi][ni][r] + bv;
            }
        }
    }
#undef STAGE_B
#undef LOAD_A
#undef WRITE_A
#undef COMPUTE
}

extern "C" void kernel_launch(void* const* d_in, const int* in_sizes, int n_in,
                              void* d_out, int out_size, void* d_ws, size_t ws_size,
                              hipStream_t stream) {
    const float* X    = (const float*)d_in[0];
    const float* W    = (const float*)d_in[1];
    const float* bias = (const float*)d_in[2];
    float* out        = (float*)d_out;
    unsigned short* Wb = (unsigned short*)d_ws;  // DP*DP bf16 = 1.18 MB

    prep_w<<<(DP * DP) / 256, 256, 0, stream>>>(W, Wb);
    fvsbn_gemm<<<(65536 / BM) * (DP / BN), 512, 0, stream>>>(X, Wb, bias, out);
}